// Round 3
// baseline (909.414 us; speedup 1.0000x reference)
//
#include <hip/hip_runtime.h>

#define NTOK 49
#define DIM 192
#define HEADS 6
#define NWIN 64
#define NBLK 4096

typedef unsigned short u16;
typedef short bf16x8 __attribute__((ext_vector_type(8)));
typedef unsigned short u16x4 __attribute__((ext_vector_type(4)));
typedef unsigned short u16x8 __attribute__((ext_vector_type(8)));
typedef float f32x4 __attribute__((ext_vector_type(4)));

#define QKVW_ELEMS (3 * DIM * DIM)   // 110592
#define PROJW_ELEMS (DIM * DIM)      // 36864

// workspace: [0, 294912) bf16 weights ; [294912, +37632) rope table
// table: [H][49][16] float2 (cos,sin) per channel-pair
#define TB_OFF_BYTES ((QKVW_ELEMS + PROJW_ELEMS) * 2)    // 294912
#define TB_QUADS     (HEADS * NTOK * 8)                   // 2352 float4

// ---- LDS map (bytes), total 54256 -> granulated 54272 -> 3 blocks/CU ----
//  A [0,27632):      xs [64][200] u16 (staging, dead after A-frag hoist)
//                    vt [192][72] u16 (V^T; last row truncated to 64 cols)
//  B [27632,47216):  kb [49][200] u16 (Q-bounce -> K -> ao; last row 192 cols)
//  C [47216,54256):  ps [49][72] u16 (last row truncated to 64 cols)
#define A_OFF 0
#define B_OFF 27632
#define C_OFF 47216
#define LDS_TOTAL 54256

__device__ __forceinline__ float bf2f(u16 u) {
    union { unsigned int i; float f; } x; x.i = ((unsigned int)u) << 16; return x.f;
}
__device__ __forceinline__ u16 f2bf(float f) {
    union { float f; unsigned int u; } x; x.f = f;
    unsigned int u = x.u;
    u += 0x7fffu + ((u >> 16) & 1u);   // RNE
    return (u16)(u >> 16);
}

extern "C" __global__ void __launch_bounds__(256)
convert_weights(const float* __restrict__ qkv_w, const float* __restrict__ proj_w,
                u16* __restrict__ ws) {
    int i = (blockIdx.x * 256 + threadIdx.x) * 4;
    if (i >= QKVW_ELEMS + PROJW_ELEMS) return;
    const float* s = (i < QKVW_ELEMS) ? (qkv_w + i) : (proj_w + (i - QKVW_ELEMS));
    float4 v = *(const float4*)s;
    ushort4 o;
    o.x = f2bf(v.x); o.y = f2bf(v.y); o.z = f2bf(v.z); o.w = f2bf(v.w);
    *(ushort4*)(ws + i) = o;
}

// rope cos/sin table: float2 (cos,sin) per (h, t, pair)
extern "C" __global__ void __launch_bounds__(256)
rope_table(const float* __restrict__ rfreq, float* __restrict__ tb) {
    int i = blockIdx.x * 256 + threadIdx.x;
    if (i >= TB_QUADS * 2) return;          // TB_QUADS*2 float2 entries
    int h = i / (NTOK * 16);
    int r = i % (NTOK * 16);
    int t = r >> 4;
    int p = r & 15;
    float tx = (float)(t % 7), ty = (float)(t / 7);
    float a = tx * rfreq[h * 16 + p] + ty * rfreq[96 + h * 16 + p];
    float2 o;
    o.x = cosf(a); o.y = sinf(a);
    ((float2*)tb)[i] = o;
}

extern "C" __global__ void __launch_bounds__(256, 3)
fused_win_attn(const float* __restrict__ x, const float* __restrict__ mask,
               const u16* __restrict__ wsq, const float* __restrict__ qkv_b,
               const u16* __restrict__ wsp, const float* __restrict__ proj_b,
               const float* __restrict__ tb, float* __restrict__ out)
{
    __shared__ __align__(16) char smem[LDS_TOTAL];
    u16* xs = (u16*)(smem + A_OFF);   // [64][200] staging
    u16* vt = (u16*)(smem + A_OFF);   // [192][72] V^T (overlays xs)
    u16* kb = (u16*)(smem + B_OFF);   // [49][200] Q-bounce -> K -> ao
    u16* ps = (u16*)(smem + C_OFF);   // [49][72]

    const int tid  = threadIdx.x;
    const int wave = tid >> 6;
    const int lane = tid & 63;
    const int ln   = lane & 15;
    const int quad = lane >> 4;
    const int blk  = blockIdx.x;
    const int widx = blk & (NWIN - 1);
    const float* xg = x + (long)blk * NTOK * DIM;
    const f32x4 fzero = {0.f, 0.f, 0.f, 0.f};
    const float2* tb2 = (const float2*)tb;
    const float scale = 0.17677669529663687f;  // 32^-0.5

    // ---- mask -> 16 registers (L2-hot gather; reused all 6 heads) ----
    float mreg[4][4];
    #pragma unroll
    for (int nt = 0; nt < 4; nt++) {
        int m = nt * 16 + ln;
        #pragma unroll
        for (int r = 0; r < 4; r++) {
            int n = wave * 16 + quad * 4 + r;
            mreg[nt][r] = (m >= NTOK) ? -1e30f
                         : ((n < NTOK) ? mask[widx * (NTOK * NTOK) + n * NTOK + m] : 0.f);
        }
    }

    // ---- stage x -> xs (bf16), zero pad token rows 49..63 ----
    for (int i = tid; i < NTOK * 48; i += 256) {
        int r = i / 48, c = (i % 48) * 4;
        float4 v = *(const float4*)(xg + r * DIM + c);
        u16x4 o = { f2bf(v.x), f2bf(v.y), f2bf(v.z), f2bf(v.w) };
        *(u16x4*)(xs + r * 200 + c) = o;
    }
    {
        u16x8 zz = {0,0,0,0,0,0,0,0};
        for (int i = tid; i < 15 * 25; i += 256) {
            int r = 49 + i / 25, c = (i % 25) * 8;
            *(u16x8*)(xs + r * 200 + c) = zz;
        }
    }
    __syncthreads();   // (1) staging complete

    // ---- hoist A-frags: own 16 token rows (6 regs) ----
    bf16x8 afr[6];
    #pragma unroll
    for (int kk = 0; kk < 6; kk++)
        afr[kk] = *(const bf16x8*)(xs + (wave * 16 + ln) * 200 + kk * 32 + quad * 8);
    __syncthreads();   // (2) xs dead -> region A free for vt

    const float ssgn = (ln & 1) ? 1.f : -1.f;   // even lane: re (-sin) ; odd: im (+sin)

    // ---- Q: token-split, jt 0..11; bounce via own kb rows; hoist qreg ----
    #pragma unroll 2
    for (int jt = 0; jt < 12; jt++) {
        bf16x8 af[6];
        const u16* wr = wsq + (jt * 16 + ln) * DIM + quad * 8;
        #pragma unroll
        for (int kk = 0; kk < 6; kk++) af[kk] = *(const bf16x8*)(wr + kk * 32);
        f32x4 acc = fzero;
        #pragma unroll
        for (int kk = 0; kk < 6; kk++)
            acc = __builtin_amdgcn_mfma_f32_16x16x32_bf16(afr[kk], af[kk], acc, 0, 0, 0);
        int ch = jt * 16 + ln;
        int hh = jt >> 1;
        int p  = ((jt & 1) << 3) + (ln >> 1);
        float b = qkv_b[ch];
        #pragma unroll
        for (int r = 0; r < 4; r++) {
            int t = wave * 16 + quad * 4 + r;
            float v = acc[r] + b;
            float prt = __shfl_xor(v, 1);
            int tl = (t < NTOK) ? t : NTOK - 1;
            float2 cs = tb2[(hh * NTOK + tl) * 16 + p];
            float o = (v * cs.x + prt * (ssgn * cs.y)) * scale;
            if (t < NTOK) kb[t * 200 + ch] = f2bf(o);
        }
    }
    // qreg hoist: own rows, same-wave in-order LDS (no barrier needed)
    bf16x8 qreg[6];
    #pragma unroll
    for (int h = 0; h < HEADS; h++)
        qreg[h] = *(const bf16x8*)(kb + (wave * 16 + ln) * 200 + h * 32 + quad * 8);

    // ---- K: token-split, jt 12..23; overwrites own Q-bounce rows ----
    #pragma unroll 2
    for (int jt = 12; jt < 24; jt++) {
        bf16x8 af[6];
        const u16* wr = wsq + (jt * 16 + ln) * DIM + quad * 8;
        #pragma unroll
        for (int kk = 0; kk < 6; kk++) af[kk] = *(const bf16x8*)(wr + kk * 32);
        f32x4 acc = fzero;
        #pragma unroll
        for (int kk = 0; kk < 6; kk++)
            acc = __builtin_amdgcn_mfma_f32_16x16x32_bf16(afr[kk], af[kk], acc, 0, 0, 0);
        int ch = (jt - 12) * 16 + ln;
        int hh = (jt - 12) >> 1;
        int p  = ((jt & 1) << 3) + (ln >> 1);
        float b = qkv_b[jt * 16 + ln];
        #pragma unroll
        for (int r = 0; r < 4; r++) {
            int t = wave * 16 + quad * 4 + r;
            float v = acc[r] + b;
            float prt = __shfl_xor(v, 1);
            int tl = (t < NTOK) ? t : NTOK - 1;
            float2 cs = tb2[(hh * NTOK + tl) * 16 + p];
            float o = v * cs.x + prt * (ssgn * cs.y);
            if (t < NTOK) kb[t * 200 + ch] = f2bf(o);
        }
    }

    // ---- V: token-split, jt 24..35; V^T into region A (zero cols t>=49) ----
    #pragma unroll 2
    for (int jt = 24; jt < 36; jt++) {
        bf16x8 af[6];
        const u16* wr = wsq + (jt * 16 + ln) * DIM + quad * 8;
        #pragma unroll
        for (int kk = 0; kk < 6; kk++) af[kk] = *(const bf16x8*)(wr + kk * 32);
        f32x4 acc = fzero;
        #pragma unroll
        for (int kk = 0; kk < 6; kk++)
            acc = __builtin_amdgcn_mfma_f32_16x16x32_bf16(afr[kk], af[kk], acc, 0, 0, 0);
        int ch = (jt - 24) * 16 + ln;
        float b = qkv_b[jt * 16 + ln];
        u16x4 pk;
        #pragma unroll
        for (int r = 0; r < 4; r++) {
            int t = wave * 16 + quad * 4 + r;
            float w = (t < NTOK) ? acc[r] + b : 0.f;
            pk[r] = f2bf(w);
        }
        *(u16x4*)(vt + ch * 72 + wave * 16 + quad * 4) = pk;
    }
    __syncthreads();   // (3) K + V^T ready for all waves

    // ---- attention: q regs, K/vt LDS; o packed in regs (ao deferred) ----
    u16x4 op0[HEADS], op1[HEADS];
    #pragma unroll
    for (int h = 0; h < HEADS; h++) {
        f32x4 s4[4];
        #pragma unroll
        for (int nt = 0; nt < 4; nt++) {
            int krow = nt * 16 + ln; if (krow > NTOK - 1) krow = NTOK - 1;
            bf16x8 bk = *(const bf16x8*)(kb + krow * 200 + h * 32 + quad * 8);
            s4[nt] = __builtin_amdgcn_mfma_f32_16x16x32_bf16(qreg[h], bk, fzero, 0, 0, 0);
        }
        #pragma unroll
        for (int nt = 0; nt < 4; nt++)
            #pragma unroll
            for (int r = 0; r < 4; r++)
                s4[nt][r] += mreg[nt][r];
        float mx[4], sm[4], rs[4];
        #pragma unroll
        for (int r = 0; r < 4; r++) {
            float v = fmaxf(fmaxf(s4[0][r], s4[1][r]), fmaxf(s4[2][r], s4[3][r]));
            #pragma unroll
            for (int d = 1; d < 16; d <<= 1) v = fmaxf(v, __shfl_xor(v, d));
            mx[r] = v; sm[r] = 0.f;
        }
        #pragma unroll
        for (int nt = 0; nt < 4; nt++) {
            int m = nt * 16 + ln;
            #pragma unroll
            for (int r = 0; r < 4; r++) {
                float e = __expf(s4[nt][r] - mx[r]);
                sm[r] += e;
                int prow = wave * 16 + quad * 4 + r;
                if (prow < NTOK) ps[prow * 72 + m] = f2bf(e);
            }
        }
        #pragma unroll
        for (int r = 0; r < 4; r++) {
            float v = sm[r];
            #pragma unroll
            for (int d = 1; d < 16; d <<= 1) v += __shfl_xor(v, d);
            rs[r] = 1.0f / v;
        }
        f32x4 o0 = fzero, o1 = fzero;
        #pragma unroll
        for (int kk = 0; kk < 2; kk++) {
            int arow = wave * 16 + ln; if (arow > NTOK - 1) arow = NTOK - 1;
            bf16x8 ap  = *(const bf16x8*)(ps + arow * 72 + kk * 32 + quad * 8);
            bf16x8 bv0 = *(const bf16x8*)(vt + (h * 32 + ln) * 72      + kk * 32 + quad * 8);
            bf16x8 bv1 = *(const bf16x8*)(vt + (h * 32 + 16 + ln) * 72 + kk * 32 + quad * 8);
            o0 = __builtin_amdgcn_mfma_f32_16x16x32_bf16(ap, bv0, o0, 0, 0, 0);
            o1 = __builtin_amdgcn_mfma_f32_16x16x32_bf16(ap, bv1, o1, 0, 0, 0);
        }
        #pragma unroll
        for (int r = 0; r < 4; r++) {
            op0[h][r] = f2bf(o0[r] * rs[r]);
            op1[h][r] = f2bf(o1[r] * rs[r]);
        }
    }
    __syncthreads();   // (4) all K/vt reads done -> kb region becomes ao

    // ---- ao write (own rows) then proj (own rows; same-wave LDS order) ----
    #pragma unroll
    for (int h = 0; h < HEADS; h++)
        #pragma unroll
        for (int r = 0; r < 4; r++) {
            int t = wave * 16 + quad * 4 + r;
            if (t < NTOK) {
                kb[t * 200 + h * 32 + ln]      = op0[h][r];
                kb[t * 200 + h * 32 + 16 + ln] = op1[h][r];
            }
        }
    bf16x8 aa[6];
    int arow = wave * 16 + ln; if (arow > NTOK - 1) arow = NTOK - 1;
    #pragma unroll
    for (int kk = 0; kk < 6; kk++)
        aa[kk] = *(const bf16x8*)(kb + arow * 200 + kk * 32 + quad * 8);
    float* ob = out + (long)blk * (NTOK * DIM);
    for (int nt = 0; nt < 12; nt++) {
        const u16* wp = wsp + (nt * 16 + ln) * DIM + quad * 8;
        f32x4 p4 = fzero;
        #pragma unroll
        for (int kk = 0; kk < 6; kk++) {
            bf16x8 bw = *(const bf16x8*)(wp + kk * 32);
            p4 = __builtin_amdgcn_mfma_f32_16x16x32_bf16(aa[kk], bw, p4, 0, 0, 0);
        }
        float bb = proj_b[nt * 16 + ln];
        #pragma unroll
        for (int r = 0; r < 4; r++) {
            int t = wave * 16 + quad * 4 + r;
            if (t < NTOK) ob[t * DIM + nt * 16 + ln] = p4[r] + bb;
        }
    }
}

extern "C" void kernel_launch(void* const* d_in, const int* in_sizes, int n_in,
                              void* d_out, int out_size, void* d_ws, size_t ws_size,
                              hipStream_t stream) {
    (void)in_sizes; (void)n_in; (void)out_size; (void)ws_size;
    u16* ws = (u16*)d_ws;
    convert_weights<<<dim3((QKVW_ELEMS + PROJW_ELEMS) / 4 / 256 + 1), dim3(256), 0, stream>>>(
        (const float*)d_in[2], (const float*)d_in[4], ws);
    float* tb = (float*)((char*)d_ws + TB_OFF_BYTES);
    rope_table<<<dim3((TB_QUADS * 2 + 255) / 256), dim3(256), 0, stream>>>(
        (const float*)d_in[6], tb);
    fused_win_attn<<<dim3(NBLK), dim3(256), 0, stream>>>(
        (const float*)d_in[0], (const float*)d_in[1],
        ws, (const float*)d_in[3],
        ws + QKVW_ELEMS, (const float*)d_in[5],
        tb, (float*)d_out);
}

// Round 4
// 582.700 us; speedup vs baseline: 1.5607x; 1.5607x over previous
//
#include <hip/hip_runtime.h>

#define NTOK 49
#define DIM 192
#define HEADS 6
#define NWIN 64
#define NBLK 4096

typedef unsigned short u16;
typedef short bf16x8 __attribute__((ext_vector_type(8)));
typedef unsigned short u16x4 __attribute__((ext_vector_type(4)));
typedef unsigned short u16x8 __attribute__((ext_vector_type(8)));
typedef float f32x4 __attribute__((ext_vector_type(4)));

#define QKVW_ELEMS (3 * DIM * DIM)   // 110592
#define PROJW_ELEMS (DIM * DIM)      // 36864

// workspace: [0, 294912) bf16 weights ; [294912, +37632) rope table
// table: [H][49][8] float4 = (cos a0, sin a0, cos a1, sin a1) per even pair p0
#define TB_OFF_BYTES ((QKVW_ELEMS + PROJW_ELEMS) * 2)    // 294912
#define TB_QUADS     (HEADS * NTOK * 8)                   // 2352 float4

// ---- LDS map (bytes), total 51232 -> 3 blocks/CU (<= 52736 proven-good) ----
//  R1 [0,24576):     xs [49][200] u16  ->  q [49][200] u16  ->  vt [192][64] u16 (XOR-swizzled)
//  K  [24576,44176): kb [49][200] u16  (K -> attn; becomes ao for proj)
//  PS [44176,51232): ps [49][72] u16
#define R1_OFF 0
#define K_OFF  24576
#define PS_OFF 44176
#define LDS_TOTAL 51232

__device__ __forceinline__ float bf2f(u16 u) {
    union { unsigned int i; float f; } x; x.i = ((unsigned int)u) << 16; return x.f;
}
__device__ __forceinline__ u16 f2bf(float f) {
    union { float f; unsigned int u; } x; x.f = f;
    unsigned int u = x.u;
    u += 0x7fffu + ((u >> 16) & 1u);   // RNE
    return (u16)(u >> 16);
}

extern "C" __global__ void __launch_bounds__(256)
convert_weights(const float* __restrict__ qkv_w, const float* __restrict__ proj_w,
                u16* __restrict__ ws) {
    int i = (blockIdx.x * 256 + threadIdx.x) * 4;
    if (i >= QKVW_ELEMS + PROJW_ELEMS) return;
    const float* s = (i < QKVW_ELEMS) ? (qkv_w + i) : (proj_w + (i - QKVW_ELEMS));
    float4 v = *(const float4*)s;
    ushort4 o;
    o.x = f2bf(v.x); o.y = f2bf(v.y); o.z = f2bf(v.z); o.w = f2bf(v.w);
    *(ushort4*)(ws + i) = o;
}

// rope cos/sin table: one float4 = (cos a0, sin a0, cos a1, sin a1) per (h, t, even pair)
extern "C" __global__ void __launch_bounds__(256)
rope_table(const float* __restrict__ rfreq, float* __restrict__ tb) {
    int i = blockIdx.x * 256 + threadIdx.x;
    if (i >= TB_QUADS) return;
    int h = i / (NTOK * 8);
    int r = i % (NTOK * 8);
    int t = r >> 3;
    int p0 = (r & 7) * 2;
    float tx = (float)(t % 7), ty = (float)(t / 7);
    float a0 = tx * rfreq[h * 16 + p0]     + ty * rfreq[96 + h * 16 + p0];
    float a1 = tx * rfreq[h * 16 + p0 + 1] + ty * rfreq[96 + h * 16 + p0 + 1];
    float4 o;
    o.x = cosf(a0); o.y = sinf(a0);
    o.z = cosf(a1); o.w = sinf(a1);
    ((float4*)tb)[i] = o;
}

extern "C" __global__ void __launch_bounds__(256, 3)
fused_win_attn(const float* __restrict__ x, const float* __restrict__ mask,
               const u16* __restrict__ wsq, const float* __restrict__ qkv_b,
               const u16* __restrict__ wsp, const float* __restrict__ proj_b,
               const float* __restrict__ tb, float* __restrict__ out)
{
    __shared__ __align__(16) char smem[LDS_TOTAL];
    u16* xs = (u16*)(smem + R1_OFF);   // staging [49][200]
    u16* qs = (u16*)(smem + R1_OFF);   // q [49][200] (after xs dead)
    u16* vt = (u16*)(smem + R1_OFF);   // V^T [192][64] swizzled (after q dead)
    u16* kb = (u16*)(smem + K_OFF);    // k [49][200] -> ao
    u16* ps = (u16*)(smem + PS_OFF);   // [49][72]

    const int tid  = threadIdx.x;
    const int wave = tid >> 6;
    const int lane = tid & 63;
    const int ln   = lane & 15;
    const int quad = lane >> 4;
    const int blk  = blockIdx.x;
    const int widx = blk & (NWIN - 1);
    const float* xg = x + (long)blk * NTOK * DIM;
    const f32x4 fzero = {0.f, 0.f, 0.f, 0.f};
    const float scale = 0.17677669529663687f;  // 32^-0.5

    // ---- mask -> 16 registers (L2-hot; reused all 6 heads) ----
    float mreg[4][4];
    #pragma unroll
    for (int nt = 0; nt < 4; nt++) {
        int m = nt * 16 + ln;
        #pragma unroll
        for (int r = 0; r < 4; r++) {
            int n = wave * 16 + quad * 4 + r;
            mreg[nt][r] = (m >= NTOK) ? -1e30f
                         : ((n < NTOK) ? mask[widx * (NTOK * NTOK) + n * NTOK + m] : 0.f);
        }
    }

    // ---- stage x -> xs (bf16), 49 real rows only (pads handled by clamps) ----
    for (int i = tid; i < NTOK * 48; i += 256) {
        int r = i / 48, c = (i % 48) * 4;
        float4 v = *(const float4*)(xg + r * DIM + c);
        u16x4 o = { f2bf(v.x), f2bf(v.y), f2bf(v.z), f2bf(v.w) };
        *(u16x4*)(xs + r * 200 + c) = o;
    }
    __syncthreads();   // (1) staging complete

    // ---- hoist B-frags (x tokens) with clamped pad rows ----
    // pad rows (>=49) carry row-48 data; every epilogue write is t<49-guarded.
    bf16x8 bfrag[6][4];
    #pragma unroll
    for (int kk = 0; kk < 6; kk++)
        #pragma unroll
        for (int nt = 0; nt < 4; nt++) {
            int row = nt * 16 + ln; if (row > NTOK - 1) row = NTOK - 1;
            bfrag[kk][nt] = *(const bf16x8*)(xs + row * 200 + kk * 32 + quad * 8);
        }
    __syncthreads();   // (2) xs dead -> region R1 free for q writes

    // ---- Q+K: channel-split, jt 0..23 (6 tiles/wave), 4-acc ILP ----
    for (int jt = wave; jt < 24; jt += 4) {
        bf16x8 af[6];
        const u16* wr = wsq + (jt * 16 + ln) * DIM + quad * 8;
        #pragma unroll
        for (int kk = 0; kk < 6; kk++) af[kk] = *(const bf16x8*)(wr + kk * 32);
        f32x4 acc[4];
        #pragma unroll
        for (int nt = 0; nt < 4; nt++) acc[nt] = fzero;
        #pragma unroll
        for (int kk = 0; kk < 6; kk++)
            #pragma unroll
            for (int nt = 0; nt < 4; nt++)
                acc[nt] = __builtin_amdgcn_mfma_f32_16x16x32_bf16(af[kk], bfrag[kk][nt], acc[nt], 0, 0, 0);

        int j0 = jt * 16 + quad * 4;
        int isq = (jt < 12);                // wave-uniform
        int c0 = j0 % DIM;
        int hh = c0 >> 5;
        int p0 = (c0 & 31) >> 1;
        float b0 = qkv_b[j0],   b1 = qkv_b[j0+1];
        float b2 = qkv_b[j0+2], b3 = qkv_b[j0+3];
        #pragma unroll
        for (int nt = 0; nt < 4; nt++) {
            int t = nt * 16 + ln;
            float v0 = acc[nt][0] + b0;
            float v1 = acc[nt][1] + b1;
            float v2 = acc[nt][2] + b2;
            float v3 = acc[nt][3] + b3;
            if (t < NTOK) {
                float4 tv = ((const float4*)tb)[(hh * NTOK + t) * 8 + (p0 >> 1)];
                float r0 = v0 * tv.x - v1 * tv.y;
                float i0 = v0 * tv.y + v1 * tv.x;
                float r1 = v2 * tv.z - v3 * tv.w;
                float i1 = v2 * tv.w + v3 * tv.z;
                if (isq) { r0 *= scale; i0 *= scale; r1 *= scale; i1 *= scale; }
                u16x4 pk = { f2bf(r0), f2bf(i0), f2bf(r1), f2bf(i1) };
                *(u16x4*)((isq ? qs : kb) + t * 200 + c0) = pk;
            }
        }
    }
    __syncthreads();   // (3) q,k complete

    // ---- hoist q fragments to registers ----
    bf16x8 qreg[6];
    {
        int qrow = wave * 16 + ln; if (qrow > NTOK - 1) qrow = NTOK - 1;
        #pragma unroll
        for (int h = 0; h < HEADS; h++)
            qreg[h] = *(const bf16x8*)(qs + qrow * 200 + h * 32 + quad * 8);
    }
    __syncthreads();   // (4) all q reads done -> region R1 free for vt

    // ---- V: channel-split, jt 24..35 (3 tiles/wave); vt [192][64] XOR-swizzled ----
    for (int jt = 24 + wave; jt < 36; jt += 4) {
        bf16x8 af[6];
        const u16* wr = wsq + (jt * 16 + ln) * DIM + quad * 8;
        #pragma unroll
        for (int kk = 0; kk < 6; kk++) af[kk] = *(const bf16x8*)(wr + kk * 32);
        f32x4 acc[4];
        #pragma unroll
        for (int nt = 0; nt < 4; nt++) acc[nt] = fzero;
        #pragma unroll
        for (int kk = 0; kk < 6; kk++)
            #pragma unroll
            for (int nt = 0; nt < 4; nt++)
                acc[nt] = __builtin_amdgcn_mfma_f32_16x16x32_bf16(af[kk], bfrag[kk][nt], acc[nt], 0, 0, 0);

        int j0 = jt * 16 + quad * 4;
        int c0 = j0 - 2 * DIM;              // V channel 0..191
        float b0 = qkv_b[j0],   b1 = qkv_b[j0+1];
        float b2 = qkv_b[j0+2], b3 = qkv_b[j0+3];
        #pragma unroll
        for (int nt = 0; nt < 4; nt++) {
            int t = nt * 16 + ln;
            float w0 = (t < NTOK) ? acc[nt][0] + b0 : 0.f;
            float w1 = (t < NTOK) ? acc[nt][1] + b1 : 0.f;
            float w2 = (t < NTOK) ? acc[nt][2] + b2 : 0.f;
            float w3 = (t < NTOK) ? acc[nt][3] + b3 : 0.f;
            vt[(c0+0) * 64 + (t ^ (((c0+0) & 7) << 3))] = f2bf(w0);
            vt[(c0+1) * 64 + (t ^ (((c0+1) & 7) << 3))] = f2bf(w1);
            vt[(c0+2) * 64 + (t ^ (((c0+2) & 7) << 3))] = f2bf(w2);
            vt[(c0+3) * 64 + (t ^ (((c0+3) & 7) << 3))] = f2bf(w3);
        }
    }
    __syncthreads();   // (5) vt ready

    // ---- attention: qreg + K(LDS) + vt(LDS, swizzled); o packed in regs ----
    u16x4 op0[HEADS], op1[HEADS];
    #pragma unroll
    for (int h = 0; h < HEADS; h++) {
        f32x4 s4[4];
        #pragma unroll
        for (int nt = 0; nt < 4; nt++) {
            int krow = nt * 16 + ln; if (krow > NTOK - 1) krow = NTOK - 1;
            bf16x8 bk = *(const bf16x8*)(kb + krow * 200 + h * 32 + quad * 8);
            s4[nt] = __builtin_amdgcn_mfma_f32_16x16x32_bf16(qreg[h], bk, fzero, 0, 0, 0);
        }
        #pragma unroll
        for (int nt = 0; nt < 4; nt++)
            #pragma unroll
            for (int r = 0; r < 4; r++)
                s4[nt][r] += mreg[nt][r];
        float mx[4], sm[4], rs[4];
        #pragma unroll
        for (int r = 0; r < 4; r++) {
            float v = fmaxf(fmaxf(s4[0][r], s4[1][r]), fmaxf(s4[2][r], s4[3][r]));
            #pragma unroll
            for (int d = 1; d < 16; d <<= 1) v = fmaxf(v, __shfl_xor(v, d));
            mx[r] = v; sm[r] = 0.f;
        }
        #pragma unroll
        for (int nt = 0; nt < 4; nt++) {
            int m = nt * 16 + ln;
            #pragma unroll
            for (int r = 0; r < 4; r++) {
                float e = __expf(s4[nt][r] - mx[r]);
                sm[r] += e;
                int prow = wave * 16 + quad * 4 + r;
                if (prow < NTOK) ps[prow * 72 + m] = f2bf(e);
            }
        }
        #pragma unroll
        for (int r = 0; r < 4; r++) {
            float v = sm[r];
            #pragma unroll
            for (int d = 1; d < 16; d <<= 1) v += __shfl_xor(v, d);
            rs[r] = 1.0f / v;
        }
        f32x4 o0 = fzero, o1 = fzero;
        int arow = wave * 16 + ln; if (arow > NTOK - 1) arow = NTOK - 1;
        int swz = (ln & 7) << 3;            // row&7 == ln&7 for both vt rows
        #pragma unroll
        for (int kk = 0; kk < 2; kk++) {
            bf16x8 ap  = *(const bf16x8*)(ps + arow * 72 + kk * 32 + quad * 8);
            int cbase = (kk * 32 + quad * 8) ^ swz;
            bf16x8 bv0 = *(const bf16x8*)(vt + (h * 32 + ln) * 64      + cbase);
            bf16x8 bv1 = *(const bf16x8*)(vt + (h * 32 + 16 + ln) * 64 + cbase);
            o0 = __builtin_amdgcn_mfma_f32_16x16x32_bf16(ap, bv0, o0, 0, 0, 0);
            o1 = __builtin_amdgcn_mfma_f32_16x16x32_bf16(ap, bv1, o1, 0, 0, 0);
        }
        #pragma unroll
        for (int r = 0; r < 4; r++) {
            op0[h][r] = f2bf(o0[r] * rs[r]);
            op1[h][r] = f2bf(o1[r] * rs[r]);
        }
    }
    __syncthreads();   // (6) all K/vt reads done -> kb region becomes ao

    // ---- ao write (own rows) then proj (own rows; same-wave LDS order) ----
    #pragma unroll
    for (int h = 0; h < HEADS; h++)
        #pragma unroll
        for (int r = 0; r < 4; r++) {
            int t = wave * 16 + quad * 4 + r;
            if (t < NTOK) {
                kb[t * 200 + h * 32 + ln]      = op0[h][r];
                kb[t * 200 + h * 32 + 16 + ln] = op1[h][r];
            }
        }
    bf16x8 aa[6];
    int arow = wave * 16 + ln; if (arow > NTOK - 1) arow = NTOK - 1;
    #pragma unroll
    for (int kk = 0; kk < 6; kk++)
        aa[kk] = *(const bf16x8*)(kb + arow * 200 + kk * 32 + quad * 8);
    float* ob = out + (long)blk * (NTOK * DIM);
    for (int nt = 0; nt < 12; nt++) {
        const u16* wp = wsp + (nt * 16 + ln) * DIM + quad * 8;
        f32x4 p4 = fzero;
        #pragma unroll
        for (int kk = 0; kk < 6; kk++) {
            bf16x8 bw = *(const bf16x8*)(wp + kk * 32);
            p4 = __builtin_amdgcn_mfma_f32_16x16x32_bf16(aa[kk], bw, p4, 0, 0, 0);
        }
        float bb = proj_b[nt * 16 + ln];
        #pragma unroll
        for (int r = 0; r < 4; r++) {
            int t = wave * 16 + quad * 4 + r;
            if (t < NTOK) ob[t * DIM + nt * 16 + ln] = p4[r] + bb;
        }
    }
}

extern "C" void kernel_launch(void* const* d_in, const int* in_sizes, int n_in,
                              void* d_out, int out_size, void* d_ws, size_t ws_size,
                              hipStream_t stream) {
    (void)in_sizes; (void)n_in; (void)out_size; (void)ws_size;
    u16* ws = (u16*)d_ws;
    convert_weights<<<dim3((QKVW_ELEMS + PROJW_ELEMS) / 4 / 256 + 1), dim3(256), 0, stream>>>(
        (const float*)d_in[2], (const float*)d_in[4], ws);
    float* tb = (float*)((char*)d_ws + TB_OFF_BYTES);
    rope_table<<<dim3((TB_QUADS + 255) / 256), dim3(256), 0, stream>>>(
        (const float*)d_in[6], tb);
    fused_win_attn<<<dim3(NBLK), dim3(256), 0, stream>>>(
        (const float*)d_in[0], (const float*)d_in[1],
        ws, (const float*)d_in[3],
        ws + QKVW_ELEMS, (const float*)d_in[5],
        tb, (float*)d_out);
}